// Round 13
// baseline (136.929 us; speedup 1.0000x reference)
//
#include <hip/hip_runtime.h>
#include <math.h>

// TopK router: logits = x @ W^T + bias; top-2; softmax over the 2; scatter.
// x: [N=16384, H=4096] fp32, W: [E=64, H=4096] fp32, bias: [64] fp32.
// d_out: [N*64] final (fp32) then [N*2] selected_experts written as floats.
//
// Round 13: rounds 10 and 12 (different LDS schemes) both hit ~92 us =
// 2.2x the 41us X-stream floor, with HBM at 2.8 TB/s. Little's law: one
// block/CU issues its 32KB X burst once per phase, completes in ~900cyc,
// then HBM idles -> ~45% duty cycle (measured = predicted). Fix: TWO
// independent blocks per CU (separate barrier clocks) so X bursts
// interleave. BLOCK=256 (4 waves = 2 kq x 2 rh), 32 rows/block, grid 512,
// 64 phases of 32k; W stage 24KB/buffer dbuf = 48KB LDS -> 2 blocks/CU.
// Fragment-major gload_lds staging + counted vmcnt(2) kept from rd12.
// Numerics byte-identical: 3-term split, PROD6, 2-way kq tree (rd8/9).

constexpr int E_EXPERTS = 64;
constexpr int H_DIM = 4096;
constexpr int BLOCK = 256;    // 4 waves = 2 kq-slices x 2 row-halves
constexpr int ROWS_B = 32;    // rows per block
constexpr int NPH = 64;       // phases; 32 k per kq-slice per phase
constexpr int KSLICE = 2048;  // k per kq slice
constexpr int REG_SH = 512;   // shorts per staged region (1 KB)
constexpr int NREG = 24;      // regions: 2 kq x 3 planes x 4 eg
constexpr int BUFS = NREG * REG_SH;  // 12288 shorts = 24 KB per buffer
constexpr int W_ELEMS = E_EXPERTS * H_DIM;

typedef __attribute__((ext_vector_type(8))) short short8;
typedef __attribute__((ext_vector_type(4))) float f32x4;

__device__ __forceinline__ float4 ld4(const float* p) {
  return *reinterpret_cast<const float4*>(p);
}

// Async global->LDS, 16B per lane: per-lane GLOBAL src, wave-uniform linear
// LDS dest (HW writes base + lane*16). Tracked by vmcnt.
__device__ __forceinline__ void gload16(const unsigned short* g,
                                        unsigned short* l) {
  __builtin_amdgcn_global_load_lds(
      (const __attribute__((address_space(1))) void*)g,
      (__attribute__((address_space(3))) void*)l, 16, 0, 0);
}

__device__ __forceinline__ unsigned short bf_rne(float x) {
  unsigned u = __builtin_bit_cast(unsigned, x);
  return (unsigned short)((u + 0x7fffu + ((u >> 16) & 1u)) >> 16);
}
__device__ __forceinline__ float bf2f(unsigned short b) {
  return __builtin_bit_cast(float, ((unsigned)b) << 16);
}
// x = h + m + l + err, |err| <= 2^-25 |x|. (h,m trunc; l RNE; residuals exact)
__device__ __forceinline__ void split3(float x, unsigned short& h,
                                       unsigned short& m, unsigned short& l) {
  unsigned short hb = (unsigned short)(__builtin_bit_cast(unsigned, x) >> 16);
  float r1 = x - bf2f(hb);
  unsigned short mb = (unsigned short)(__builtin_bit_cast(unsigned, r1) >> 16);
  float r2 = r1 - bf2f(mb);
  h = hb;
  m = mb;
  l = bf_rne(r2);
}
__device__ __forceinline__ void split3_8(float4 a, float4 b, short8& h,
                                         short8& m, short8& l) {
  unsigned short hh, mm, ll;
  split3(a.x, hh, mm, ll); h[0] = (short)hh; m[0] = (short)mm; l[0] = (short)ll;
  split3(a.y, hh, mm, ll); h[1] = (short)hh; m[1] = (short)mm; l[1] = (short)ll;
  split3(a.z, hh, mm, ll); h[2] = (short)hh; m[2] = (short)mm; l[2] = (short)ll;
  split3(a.w, hh, mm, ll); h[3] = (short)hh; m[3] = (short)mm; l[3] = (short)ll;
  split3(b.x, hh, mm, ll); h[4] = (short)hh; m[4] = (short)mm; l[4] = (short)ll;
  split3(b.y, hh, mm, ll); h[5] = (short)hh; m[5] = (short)mm; l[5] = (short)ll;
  split3(b.z, hh, mm, ll); h[6] = (short)hh; m[6] = (short)mm; l[6] = (short)ll;
  split3(b.w, hh, mm, ll); h[7] = (short)hh; m[7] = (short)mm; l[7] = (short)ll;
}

// Pre-kernel: split W into h/m/l bf16 planes (same math as split3).
__global__ __launch_bounds__(256) void split_w_kernel(
    const float* __restrict__ w, unsigned short* __restrict__ wh,
    unsigned short* __restrict__ wm, unsigned short* __restrict__ wl) {
  const int i = (blockIdx.x * 256 + threadIdx.x) * 4;
  float4 v = ld4(w + i);
  ushort4 h4, m4, l4;
  split3(v.x, h4.x, m4.x, l4.x);
  split3(v.y, h4.y, m4.y, l4.y);
  split3(v.z, h4.z, m4.z, l4.z);
  split3(v.w, h4.w, m4.w, l4.w);
  *reinterpret_cast<ushort4*>(wh + i) = h4;
  *reinterpret_cast<ushort4*>(wm + i) = m4;
  *reinterpret_cast<ushort4*>(wl + i) = l4;
}

__global__ __launch_bounds__(BLOCK, 2) void topk_router_mfma(
    const float* __restrict__ x, const unsigned short* __restrict__ wh,
    const unsigned short* __restrict__ wm,
    const unsigned short* __restrict__ wl, const float* __restrict__ bias,
    float* __restrict__ out_final, float* __restrict__ out_idx) {
  __shared__ unsigned short smem_s[2 * BUFS];  // 49152 B; fp32 partials alias

  const int tid = threadIdx.x;
  const int lane = tid & 63;
  const int wid = tid >> 6;
  const int kq = wid & 1;   // K slice (2048 k)
  const int rh = wid >> 1;  // row half (16 rows)
  const int rowBase = blockIdx.x * ROWS_B;
  const int lr = lane & 15;
  const int kg = lane >> 4;

  // Staging: 24 regions (kq,pl,eg) of 1 KB; wave w stages r = 6w+i, i=0..5.
  // Region r: kq=r/12, pl=(r%12)>>2, eg=r&3. Lane ll holds
  // W_pl[eg*16 + (ll&15)][kq*2048 + t*32 + (ll>>4)*8 ..+8) at slot ll*16B.
#define DECL_RG(i)                                                       \
  const int r##i = wid * 6 + (i);                                        \
  const int q##i = r##i >> 2;                                            \
  const int rkq##i = q##i / 3;                                           \
  const int rpl##i = q##i - rkq##i * 3;                                  \
  const unsigned short* gb##i =                                          \
      (rpl##i == 0 ? wh : (rpl##i == 1 ? wm : wl)) +                     \
      (size_t)((r##i & 3) * 16 + lr) * H_DIM + rkq##i * KSLICE + kg * 8; \
  unsigned short* lb##i = &smem_s[r##i * REG_SH];
  DECL_RG(0) DECL_RG(1) DECL_RG(2) DECL_RG(3) DECL_RG(4) DECL_RG(5)

#define STAGE(t, buf)                                  \
  do {                                                 \
    gload16(gb0 + (size_t)(t) * 32, lb0 + (buf)*BUFS); \
    gload16(gb1 + (size_t)(t) * 32, lb1 + (buf)*BUFS); \
    gload16(gb2 + (size_t)(t) * 32, lb2 + (buf)*BUFS); \
    gload16(gb3 + (size_t)(t) * 32, lb3 + (buf)*BUFS); \
    gload16(gb4 + (size_t)(t) * 32, lb4 + (buf)*BUFS); \
    gload16(gb5 + (size_t)(t) * 32, lb5 + (buf)*BUFS); \
  } while (0)

  // X: this wave's 16 rows (1 A-frag) x its 2048-k slice.
  const float* __restrict__ xr0 =
      x + (size_t)(rowBase + rh * 16 + lr) * H_DIM + kq * KSLICE + kg * 8;

  float4 xA0, xA1, xB0, xB1;
#define XLOADA(t)                          \
  do {                                     \
    xA0 = ld4(xr0 + (size_t)(t) * 32);     \
    xA1 = ld4(xr0 + (size_t)(t) * 32 + 4); \
  } while (0)
#define XLOADB(t)                          \
  do {                                     \
    xB0 = ld4(xr0 + (size_t)(t) * 32);     \
    xB1 = ld4(xr0 + (size_t)(t) * 32 + 4); \
  } while (0)

  f32x4 acc0 = {0.f, 0.f, 0.f, 0.f}, acc1 = acc0, acc2 = acc0, acc3 = acc0;

  // Prologue: stage tile0 -> buf0; X phases 0,1 -> regs; full drain once.
  STAGE(0, 0);
  __builtin_amdgcn_sched_barrier(0);
  XLOADA(0);
  XLOADB(1);
  asm volatile("s_waitcnt vmcnt(0)" ::: "memory");
  __builtin_amdgcn_s_barrier();
  __builtin_amdgcn_sched_barrier(0);

  // Consumer: contiguous 1KB per (eg,pl) region, slot = lane*16B.
#define FRAG(buf, eg, pl)                                                  \
  (*reinterpret_cast<const short8*>(                                       \
      &smem_s[(size_t)(buf)*BUFS + ((kq * 3 + (pl)) * 4 + (eg)) * REG_SH + \
              lane * 8]))

#define MM(d, a, b) d = __builtin_amdgcn_mfma_f32_16x16x32_bf16(a, b, d, 0, 0, 0)
#define PROD6(d, Ah, Am, Al, Bh, Bm, Bl)                      \
  MM(d, Ah, Bh); MM(d, Ah, Bm); MM(d, Am, Bh); MM(d, Am, Bm); \
  MM(d, Ah, Bl); MM(d, Al, Bh)

#define PHASE(p, buf, X0, X1, XLOADM)                                   \
  do {                                                                  \
    if ((p) + 1 < NPH) STAGE((p) + 1, (buf) ^ 1); /* async, counted */  \
    __builtin_amdgcn_sched_barrier(0); /* stage = oldest vmem ops */    \
    short8 b0h = FRAG(buf, 0, 0), b0m = FRAG(buf, 0, 1),                \
           b0l = FRAG(buf, 0, 2);                                       \
    short8 b1h = FRAG(buf, 1, 0), b1m = FRAG(buf, 1, 1),                \
           b1l = FRAG(buf, 1, 2);                                       \
    short8 b2h = FRAG(buf, 2, 0), b2m = FRAG(buf, 2, 1),                \
           b2l = FRAG(buf, 2, 2);                                       \
    short8 b3h = FRAG(buf, 3, 0), b3m = FRAG(buf, 3, 1),                \
           b3l = FRAG(buf, 3, 2);                                       \
    short8 ah, am, al;                                                  \
    split3_8(X0, X1, ah, am, al);       /* consume X(p) FIRST */        \
    if ((p) + 2 < NPH) XLOADM((p) + 2); /* THEN prefetch into X regs */ \
    PROD6(acc0, ah, am, al, b0h, b0m, b0l);                             \
    PROD6(acc1, ah, am, al, b1h, b1m, b1l);                             \
    PROD6(acc2, ah, am, al, b2h, b2m, b2l);                             \
    PROD6(acc3, ah, am, al, b3h, b3m, b3l);                             \
    if ((p) + 2 < NPH) {                                                \
      asm volatile("s_waitcnt vmcnt(2)" ::: "memory"); /* stage done */ \
    } else {                                                            \
      asm volatile("s_waitcnt vmcnt(0)" ::: "memory"); /* tail drain */ \
    }                                                                   \
    __builtin_amdgcn_s_barrier();                                       \
    __builtin_amdgcn_sched_barrier(0);                                  \
  } while (0)

  for (int p = 0; p < NPH; p += 2) {
    PHASE(p, 0, xA0, xA1, XLOADA);
    PHASE(p + 1, 1, xB0, xB1, XLOADB);
  }

  // Partials: part[kq][row][e], row pad 68 floats (17408 B, aliased; loop
  // ended with vmcnt(0)+barrier so all stage ops and reads are done).
  float* part = reinterpret_cast<float*>(smem_s);
  const int pr = rh * 16 + kg * 4;  // output rows of this wave's frag
#define PSTORE(A, g)                                      \
  part[(size_t)(kq * 32 + pr + 0) * 68 + (g)*16 + lr] = A[0]; \
  part[(size_t)(kq * 32 + pr + 1) * 68 + (g)*16 + lr] = A[1]; \
  part[(size_t)(kq * 32 + pr + 2) * 68 + (g)*16 + lr] = A[2]; \
  part[(size_t)(kq * 32 + pr + 3) * 68 + (g)*16 + lr] = A[3];
  PSTORE(acc0, 0)
  PSTORE(acc1, 1)
  PSTORE(acc2, 2)
  PSTORE(acc3, 3)
  asm volatile("s_waitcnt lgkmcnt(0)" ::: "memory");
  __builtin_amdgcn_s_barrier();

  // Epilogue: 8 threads/row, 8 experts each; ordered 2-way partial sum,
  // stable top-2 scan, shfl_xor merge, softmax, scatter.
  const int r = tid >> 3;
  const int eb = (tid & 7) * 8;
  const int n = rowBase + r;

  float v8[8];
#pragma unroll
  for (int j = 0; j < 8; ++j) {
    int e = eb + j;
    v8[j] = (part[(size_t)(0 * 32 + r) * 68 + e] +
             part[(size_t)(1 * 32 + r) * 68 + e]) +
            bias[e];
  }

  float av = -INFINITY, bv = -INFINITY;
  int ai = E_EXPERTS, bi = E_EXPERTS;
#pragma unroll
  for (int j = 0; j < 8; ++j) {
    int e = eb + j;
    float v = v8[j];
    bool beats_a = (v > av) || (v == av && e < ai);
    bool beats_b = (v > bv) || (v == bv && e < bi);
    if (beats_a) {
      bv = av; bi = ai; av = v; ai = e;
    } else if (beats_b) {
      bv = v; bi = e;
    }
  }
#pragma unroll
  for (int d = 1; d < 8; d <<= 1) {
    float av2 = __shfl_xor(av, d);
    float bv2 = __shfl_xor(bv, d);
    int ai2 = __shfl_xor(ai, d);
    int bi2 = __shfl_xor(bi, d);
    bool afirst = (av > av2) || (av == av2 && ai < ai2);
    float na, nb;
    int nai, nbi;
    if (afirst) {
      na = av; nai = ai;
      bool t = (bv > av2) || (bv == av2 && bi < ai2);
      nb = t ? bv : av2;
      nbi = t ? bi : ai2;
    } else {
      na = av2; nai = ai2;
      bool t = (av > bv2) || (av == bv2 && ai < bi2);
      nb = t ? av : bv2;
      nbi = t ? ai : bi2;
    }
    av = na; ai = nai; bv = nb; bi = nbi;
  }

  float e1 = expf(bv - av);
  float denom = 1.0f + e1;
  float p0 = 1.0f / denom;
  float p1 = e1 / denom;

#pragma unroll
  for (int i = 0; i < 2; ++i) {
    float4 o4;
    float* po = &o4.x;
#pragma unroll
    for (int j = 0; j < 4; ++j) {
      int e = eb + i * 4 + j;
      po[j] = (e == ai) ? p0 : (e == bi) ? p1 : 0.0f;
    }
    *reinterpret_cast<float4*>(&out_final[(size_t)n * E_EXPERTS + eb + i * 4]) =
        o4;
  }
  if ((tid & 7) == 0) {
    out_idx[(size_t)n * 2 + 0] = (float)ai;
    out_idx[(size_t)n * 2 + 1] = (float)bi;
  }
}

extern "C" void kernel_launch(void* const* d_in, const int* in_sizes, int n_in,
                              void* d_out, int out_size, void* d_ws,
                              size_t ws_size, hipStream_t stream) {
  const float* x = (const float*)d_in[0];
  const float* w = (const float*)d_in[1];
  const float* bias = (const float*)d_in[2];
  const int N = in_sizes[0] / H_DIM;  // 16384
  float* out_final = (float*)d_out;
  float* out_idx = out_final + (size_t)N * E_EXPERTS;

  unsigned short* wh = (unsigned short*)d_ws;  // 3 planes x 512 KB
  unsigned short* wm = wh + W_ELEMS;
  unsigned short* wl = wm + W_ELEMS;

  split_w_kernel<<<W_ELEMS / (256 * 4), 256, 0, stream>>>(w, wh, wm, wl);
  topk_router_mfma<<<N / ROWS_B, BLOCK, 0, stream>>>(x, wh, wm, wl, bias,
                                                     out_final, out_idx);
}

// Round 14
// 133.914 us; speedup vs baseline: 1.0225x; 1.0225x over previous
//
#include <hip/hip_runtime.h>
#include <math.h>

// TopK router: logits = x @ W^T + bias; top-2; softmax over the 2; scatter.
// x: [N=16384, H=4096] fp32, W: [E=64, H=4096] fp32, bias: [64] fp32.
// d_out: [N*64] final (fp32) then [N*2] selected_experts written as floats.
//
// Round 14: rounds 8-13 all clocked phases at the SERIAL SUM of per-CU pipe
// demands (X-HBM 3200 + W-L2 860 + LDS 1150 + VALU 560 + MFMA 480 + barrier
// ~= measured 6900 cyc): the per-phase s_barrier re-syncs all waves, so the
// CU bursts one pipe at a time and each pipe idles ~80% of the phase. Fix:
// NO barriers in the K loop. Each wave is fully independent: 32 rows
// (2 A-frags) x one K-quarter x all 64 experts; W read per-lane from the
// L2-resident pre-split planes into NAMED cur/nxt register sets (cross-
// iteration dbuf -> loads must issue a chunk early; can't sink across the
// back-edge), X prefetched 2 chunks ahead (A/B sets). Waves drift out of
// phase and pipe demands interleave. LDS only for the final 4-way kq
// partial reduce (one barrier total). Numerics byte-identical to rounds
// 10/12: 3-term split, PROD6 order, 4-way kq tree.

constexpr int E_EXPERTS = 64;
constexpr int H_DIM = 4096;
constexpr int BLOCK = 512;    // 8 waves = 4 kq-slices x 2 row-halves
constexpr int ROWS_B = 64;    // rows per block
constexpr int KSLICE = 1024;  // k per kq slice
constexpr int NCH = 32;       // 32-k chunks per slice
constexpr int W_ELEMS = E_EXPERTS * H_DIM;

typedef __attribute__((ext_vector_type(8))) short short8;
typedef __attribute__((ext_vector_type(4))) float f32x4;

__device__ __forceinline__ float4 ld4(const float* p) {
  return *reinterpret_cast<const float4*>(p);
}
__device__ __forceinline__ short8 lds8(const unsigned short* p) {
  return *reinterpret_cast<const short8*>(p);
}

__device__ __forceinline__ unsigned short bf_rne(float x) {
  unsigned u = __builtin_bit_cast(unsigned, x);
  return (unsigned short)((u + 0x7fffu + ((u >> 16) & 1u)) >> 16);
}
__device__ __forceinline__ float bf2f(unsigned short b) {
  return __builtin_bit_cast(float, ((unsigned)b) << 16);
}
// x = h + m + l + err, |err| <= 2^-25 |x|. (h,m trunc; l RNE; residuals exact)
__device__ __forceinline__ void split3(float x, unsigned short& h,
                                       unsigned short& m, unsigned short& l) {
  unsigned short hb = (unsigned short)(__builtin_bit_cast(unsigned, x) >> 16);
  float r1 = x - bf2f(hb);
  unsigned short mb = (unsigned short)(__builtin_bit_cast(unsigned, r1) >> 16);
  float r2 = r1 - bf2f(mb);
  h = hb;
  m = mb;
  l = bf_rne(r2);
}
__device__ __forceinline__ void split3_8(float4 a, float4 b, short8& h,
                                         short8& m, short8& l) {
  unsigned short hh, mm, ll;
  split3(a.x, hh, mm, ll); h[0] = (short)hh; m[0] = (short)mm; l[0] = (short)ll;
  split3(a.y, hh, mm, ll); h[1] = (short)hh; m[1] = (short)mm; l[1] = (short)ll;
  split3(a.z, hh, mm, ll); h[2] = (short)hh; m[2] = (short)mm; l[2] = (short)ll;
  split3(a.w, hh, mm, ll); h[3] = (short)hh; m[3] = (short)mm; l[3] = (short)ll;
  split3(b.x, hh, mm, ll); h[4] = (short)hh; m[4] = (short)mm; l[4] = (short)ll;
  split3(b.y, hh, mm, ll); h[5] = (short)hh; m[5] = (short)mm; l[5] = (short)ll;
  split3(b.z, hh, mm, ll); h[6] = (short)hh; m[6] = (short)mm; l[6] = (short)ll;
  split3(b.w, hh, mm, ll); h[7] = (short)hh; m[7] = (short)mm; l[7] = (short)ll;
}

// Pre-kernel: split W into h/m/l bf16 planes (same math as split3).
__global__ __launch_bounds__(256) void split_w_kernel(
    const float* __restrict__ w, unsigned short* __restrict__ wh,
    unsigned short* __restrict__ wm, unsigned short* __restrict__ wl) {
  const int i = (blockIdx.x * 256 + threadIdx.x) * 4;
  float4 v = ld4(w + i);
  ushort4 h4, m4, l4;
  split3(v.x, h4.x, m4.x, l4.x);
  split3(v.y, h4.y, m4.y, l4.y);
  split3(v.z, h4.z, m4.z, l4.z);
  split3(v.w, h4.w, m4.w, l4.w);
  *reinterpret_cast<ushort4*>(wh + i) = h4;
  *reinterpret_cast<ushort4*>(wm + i) = m4;
  *reinterpret_cast<ushort4*>(wl + i) = l4;
}

__global__ __launch_bounds__(BLOCK, 2) void topk_router_mfma(
    const float* __restrict__ x, const unsigned short* __restrict__ wh,
    const unsigned short* __restrict__ wm,
    const unsigned short* __restrict__ wl, const float* __restrict__ bias,
    float* __restrict__ out_final, float* __restrict__ out_idx) {
  __shared__ float part[4 * ROWS_B * 68];  // 69632 B, only for final reduce

  const int tid = threadIdx.x;
  const int lane = tid & 63;
  const int wid = tid >> 6;
  const int kq = wid & 3;   // K slice (1024 k)
  const int rh = wid >> 2;  // row half (32 rows)
  const int rowBase = blockIdx.x * ROWS_B;
  const int lr = lane & 15;
  const int kg = lane >> 4;

  // Per-lane W pointers: B-frag row = expert eg*16+lr, k-base kq*1024+kg*8.
  const size_t wo = (size_t)lr * H_DIM + kq * KSLICE + kg * 8;
  const unsigned short* __restrict__ wh0 = wh + wo;
  const unsigned short* __restrict__ wh1 = wh0 + (size_t)16 * H_DIM;
  const unsigned short* __restrict__ wh2 = wh0 + (size_t)32 * H_DIM;
  const unsigned short* __restrict__ wh3 = wh0 + (size_t)48 * H_DIM;
  const unsigned short* __restrict__ wm0 = wm + wo;
  const unsigned short* __restrict__ wm1 = wm0 + (size_t)16 * H_DIM;
  const unsigned short* __restrict__ wm2 = wm0 + (size_t)32 * H_DIM;
  const unsigned short* __restrict__ wm3 = wm0 + (size_t)48 * H_DIM;
  const unsigned short* __restrict__ wl0 = wl + wo;
  const unsigned short* __restrict__ wl1 = wl0 + (size_t)16 * H_DIM;
  const unsigned short* __restrict__ wl2 = wl0 + (size_t)32 * H_DIM;
  const unsigned short* __restrict__ wl3 = wl0 + (size_t)48 * H_DIM;

  // X: this wave's 32 rows (2 A-frags) x its 1024-k slice.
  const float* __restrict__ xr0 =
      x + (size_t)(rowBase + rh * 32 + lr) * H_DIM + kq * KSLICE + kg * 8;
  const float* __restrict__ xr1 = xr0 + (size_t)16 * H_DIM;

  // Named W register sets (cur = w*, nxt = v*), 12 short8 each.
  short8 w0h, w1h, w2h, w3h, w0m, w1m, w2m, w3m, w0l, w1l, w2l, w3l;
  short8 v0h, v1h, v2h, v3h, v0m, v1m, v2m, v3m, v0l, v1l, v2l, v3l;

#define WLOAD(P, t)                                \
  do {                                             \
    const size_t o_ = (size_t)(t) * 32;            \
    P##0h = lds8(wh0 + o_); P##1h = lds8(wh1 + o_); \
    P##2h = lds8(wh2 + o_); P##3h = lds8(wh3 + o_); \
    P##0m = lds8(wm0 + o_); P##1m = lds8(wm1 + o_); \
    P##2m = lds8(wm2 + o_); P##3m = lds8(wm3 + o_); \
    P##0l = lds8(wl0 + o_); P##1l = lds8(wl1 + o_); \
    P##2l = lds8(wl2 + o_); P##3l = lds8(wl3 + o_); \
  } while (0)

  float4 xA0, xA1, xA2, xA3, xB0, xB1, xB2, xB3;
#define XLOADA(t)                          \
  do {                                     \
    xA0 = ld4(xr0 + (size_t)(t) * 32);     \
    xA1 = ld4(xr0 + (size_t)(t) * 32 + 4); \
    xA2 = ld4(xr1 + (size_t)(t) * 32);     \
    xA3 = ld4(xr1 + (size_t)(t) * 32 + 4); \
  } while (0)
#define XLOADB(t)                          \
  do {                                     \
    xB0 = ld4(xr0 + (size_t)(t) * 32);     \
    xB1 = ld4(xr0 + (size_t)(t) * 32 + 4); \
    xB2 = ld4(xr1 + (size_t)(t) * 32);     \
    xB3 = ld4(xr1 + (size_t)(t) * 32 + 4); \
  } while (0)

  f32x4 accA0 = {0.f, 0.f, 0.f, 0.f}, accA1 = accA0, accA2 = accA0,
        accA3 = accA0, accB0 = accA0, accB1 = accA0, accB2 = accA0,
        accB3 = accA0;

#define MM(d, a, b) d = __builtin_amdgcn_mfma_f32_16x16x32_bf16(a, b, d, 0, 0, 0)
#define PROD6(d, Ah, Am, Al, Bh, Bm, Bl)                      \
  MM(d, Ah, Bh); MM(d, Ah, Bm); MM(d, Am, Bh); MM(d, Am, Bm); \
  MM(d, Ah, Bl); MM(d, Al, Bh)
// All 48 MFMAs of one chunk against W set P (order = rounds 10/12).
#define MFMA48(P, A0h, A0m, A0l, A1h, A1m, A1l)        \
  do {                                                 \
    PROD6(accA0, A0h, A0m, A0l, P##0h, P##0m, P##0l);  \
    PROD6(accA1, A0h, A0m, A0l, P##1h, P##1m, P##1l);  \
    PROD6(accA2, A0h, A0m, A0l, P##2h, P##2m, P##2l);  \
    PROD6(accA3, A0h, A0m, A0l, P##3h, P##3m, P##3l);  \
    PROD6(accB0, A1h, A1m, A1l, P##0h, P##0m, P##0l);  \
    PROD6(accB1, A1h, A1m, A1l, P##1h, P##1m, P##1l);  \
    PROD6(accB2, A1h, A1m, A1l, P##2h, P##2m, P##2l);  \
    PROD6(accB3, A1h, A1m, A1l, P##3h, P##3m, P##3l);  \
  } while (0)

  // Prologue: W chunk0 -> cur; X chunks 0,1 -> A,B.
  WLOAD(w, 0);
  XLOADA(0);
  XLOADB(1);

  short8 a0h, a0m, a0l, a1h, a1m, a1l;
  for (int c = 0; c < NCH; c += 2) {
    // ---- chunk c: consume cur(w) + xA ----
    WLOAD(v, c + 1);  // issue nxt a chunk early (cross-iter dataflow)
    split3_8(xA0, xA1, a0h, a0m, a0l);
    split3_8(xA2, xA3, a1h, a1m, a1l);
    if (c + 2 < NCH) XLOADA(c + 2);  // X 2 chunks ahead
    MFMA48(w, a0h, a0m, a0l, a1h, a1m, a1l);
    // ---- chunk c+1: consume nxt(v) + xB ----
    if (c + 2 < NCH) WLOAD(w, c + 2);  // refill cur for next iteration
    split3_8(xB0, xB1, a0h, a0m, a0l);
    split3_8(xB2, xB3, a1h, a1m, a1l);
    if (c + 3 < NCH) XLOADB(c + 3);
    MFMA48(v, a0h, a0m, a0l, a1h, a1m, a1l);
  }

  // Partials: part[kq][row][e], row pad 68 floats.
  const int pr = kg * 4;
  const int rwA = rh * 32 + pr;       // frag0 rows
  const int rwB = rh * 32 + 16 + pr;  // frag1 rows
#define PSTORE(A, rw, g)                                        \
  part[(size_t)(kq * 64 + (rw) + 0) * 68 + (g)*16 + lr] = A[0]; \
  part[(size_t)(kq * 64 + (rw) + 1) * 68 + (g)*16 + lr] = A[1]; \
  part[(size_t)(kq * 64 + (rw) + 2) * 68 + (g)*16 + lr] = A[2]; \
  part[(size_t)(kq * 64 + (rw) + 3) * 68 + (g)*16 + lr] = A[3];
  PSTORE(accA0, rwA, 0)
  PSTORE(accA1, rwA, 1)
  PSTORE(accA2, rwA, 2)
  PSTORE(accA3, rwA, 3)
  PSTORE(accB0, rwB, 0)
  PSTORE(accB1, rwB, 1)
  PSTORE(accB2, rwB, 2)
  PSTORE(accB3, rwB, 3)
  __syncthreads();  // the only block-wide barrier

  // Epilogue: 8 threads/row, 8 experts each; ordered 4-way partial sum,
  // stable top-2 scan, shfl_xor merge, softmax, scatter.
  const int r = tid >> 3;
  const int eb = (tid & 7) * 8;
  const int n = rowBase + r;

  float v8[8];
#pragma unroll
  for (int j = 0; j < 8; ++j) {
    int e = eb + j;
    v8[j] = ((part[(size_t)(0 * 64 + r) * 68 + e] +
              part[(size_t)(1 * 64 + r) * 68 + e]) +
             (part[(size_t)(2 * 64 + r) * 68 + e] +
              part[(size_t)(3 * 64 + r) * 68 + e])) +
            bias[e];
  }

  float av = -INFINITY, bv = -INFINITY;
  int ai = E_EXPERTS, bi = E_EXPERTS;
#pragma unroll
  for (int j = 0; j < 8; ++j) {
    int e = eb + j;
    float v = v8[j];
    bool beats_a = (v > av) || (v == av && e < ai);
    bool beats_b = (v > bv) || (v == bv && e < bi);
    if (beats_a) {
      bv = av; bi = ai; av = v; ai = e;
    } else if (beats_b) {
      bv = v; bi = e;
    }
  }
#pragma unroll
  for (int d = 1; d < 8; d <<= 1) {
    float av2 = __shfl_xor(av, d);
    float bv2 = __shfl_xor(bv, d);
    int ai2 = __shfl_xor(ai, d);
    int bi2 = __shfl_xor(bi, d);
    bool afirst = (av > av2) || (av == av2 && ai < ai2);
    float na, nb;
    int nai, nbi;
    if (afirst) {
      na = av; nai = ai;
      bool t = (bv > av2) || (bv == av2 && bi < ai2);
      nb = t ? bv : av2;
      nbi = t ? bi : ai2;
    } else {
      na = av2; nai = ai2;
      bool t = (av > bv2) || (av == bv2 && ai < bi2);
      nb = t ? av : bv2;
      nbi = t ? ai : bi2;
    }
    av = na; ai = nai; bv = nb; bi = nbi;
  }

  float e1 = expf(bv - av);
  float denom = 1.0f + e1;
  float p0 = 1.0f / denom;
  float p1 = e1 / denom;

#pragma unroll
  for (int i = 0; i < 2; ++i) {
    float4 o4;
    float* po = &o4.x;
#pragma unroll
    for (int j = 0; j < 4; ++j) {
      int e = eb + i * 4 + j;
      po[j] = (e == ai) ? p0 : (e == bi) ? p1 : 0.0f;
    }
    *reinterpret_cast<float4*>(&out_final[(size_t)n * E_EXPERTS + eb + i * 4]) =
        o4;
  }
  if ((tid & 7) == 0) {
    out_idx[(size_t)n * 2 + 0] = (float)ai;
    out_idx[(size_t)n * 2 + 1] = (float)bi;
  }
}

extern "C" void kernel_launch(void* const* d_in, const int* in_sizes, int n_in,
                              void* d_out, int out_size, void* d_ws,
                              size_t ws_size, hipStream_t stream) {
  const float* x = (const float*)d_in[0];
  const float* w = (const float*)d_in[1];
  const float* bias = (const float*)d_in[2];
  const int N = in_sizes[0] / H_DIM;  // 16384
  float* out_final = (float*)d_out;
  float* out_idx = out_final + (size_t)N * E_EXPERTS;

  unsigned short* wh = (unsigned short*)d_ws;  // 3 planes x 512 KB
  unsigned short* wm = wh + W_ELEMS;
  unsigned short* wl = wm + W_ELEMS;

  split_w_kernel<<<W_ELEMS / (256 * 4), 256, 0, stream>>>(w, wh, wm, wl);
  topk_router_mfma<<<N / ROWS_B, BLOCK, 0, stream>>>(x, wh, wm, wl, bias,
                                                     out_final, out_idx);
}

// Round 15
// 93.782 us; speedup vs baseline: 1.4601x; 1.4279x over previous
//
#include <hip/hip_runtime.h>
#include <math.h>

// TopK router: logits = x @ W^T + bias; top-2; softmax over the 2; scatter.
// x: [N=16384, H=4096] fp32, W: [E=64, H=4096] fp32, bias: [64] fp32.
// d_out: [N*64] final (fp32) then [N*2] selected_experts written as floats.
//
// Round 15 = round 12 (fragment-major 1KB W regions staged via
// global_load_lds; conflict-free ds_read_b128; counted vmcnt + raw
// barriers) + two fixes found by re-audit:
// 1) vmcnt(2) -> vmcnt(4): issue order is [6 stage][...][4 X ld4], so
//    vmcnt(2) forced half the X prefetch (meant for phase p+2) to land in
//    phase p -- re-exposing ~900cyc HBM latency per phase. vmcnt(4) drains
//    exactly the stage and leaves all 4 X loads in flight (1.5-phase cover).
// 2) PROD6 put 6 serially-dependent MFMAs (same acc) back-to-back;
//    interleave the 8 accs term-by-term (8 independent MFMAs between
//    dependent reuses). Per-acc product order unchanged -> bit-identical.
// W-in-registers is abandoned for good: rounds 2/3/6/14 all collapsed in
// regalloc (VGPR 52-112) and serialized on load latency.

constexpr int E_EXPERTS = 64;
constexpr int H_DIM = 4096;
constexpr int BLOCK = 512;    // 8 waves = 4 kq-slices x 2 row-halves
constexpr int ROWS_B = 64;    // rows per block
constexpr int NPH = 32;       // phases; 32 k per kq-slice per phase
constexpr int KSLICE = 1024;  // k per kq slice
constexpr int REG_SH = 512;   // shorts per staged region (1 KB)
constexpr int BUFS = 48 * REG_SH;  // 24576 shorts = 48 KB per buffer
constexpr int W_ELEMS = E_EXPERTS * H_DIM;

typedef __attribute__((ext_vector_type(8))) short short8;
typedef __attribute__((ext_vector_type(4))) float f32x4;

__device__ __forceinline__ float4 ld4(const float* p) {
  return *reinterpret_cast<const float4*>(p);
}

// Async global->LDS, 16B per lane: per-lane GLOBAL src, wave-uniform linear
// LDS dest (HW writes base + lane*16). Tracked by vmcnt.
__device__ __forceinline__ void gload16(const unsigned short* g,
                                        unsigned short* l) {
  __builtin_amdgcn_global_load_lds(
      (const __attribute__((address_space(1))) void*)g,
      (__attribute__((address_space(3))) void*)l, 16, 0, 0);
}

__device__ __forceinline__ unsigned short bf_rne(float x) {
  unsigned u = __builtin_bit_cast(unsigned, x);
  return (unsigned short)((u + 0x7fffu + ((u >> 16) & 1u)) >> 16);
}
__device__ __forceinline__ float bf2f(unsigned short b) {
  return __builtin_bit_cast(float, ((unsigned)b) << 16);
}
// x = h + m + l + err, |err| <= 2^-25 |x|. (h,m trunc; l RNE; residuals exact)
__device__ __forceinline__ void split3(float x, unsigned short& h,
                                       unsigned short& m, unsigned short& l) {
  unsigned short hb = (unsigned short)(__builtin_bit_cast(unsigned, x) >> 16);
  float r1 = x - bf2f(hb);
  unsigned short mb = (unsigned short)(__builtin_bit_cast(unsigned, r1) >> 16);
  float r2 = r1 - bf2f(mb);
  h = hb;
  m = mb;
  l = bf_rne(r2);
}
__device__ __forceinline__ void split3_8(float4 a, float4 b, short8& h,
                                         short8& m, short8& l) {
  unsigned short hh, mm, ll;
  split3(a.x, hh, mm, ll); h[0] = (short)hh; m[0] = (short)mm; l[0] = (short)ll;
  split3(a.y, hh, mm, ll); h[1] = (short)hh; m[1] = (short)mm; l[1] = (short)ll;
  split3(a.z, hh, mm, ll); h[2] = (short)hh; m[2] = (short)mm; l[2] = (short)ll;
  split3(a.w, hh, mm, ll); h[3] = (short)hh; m[3] = (short)mm; l[3] = (short)ll;
  split3(b.x, hh, mm, ll); h[4] = (short)hh; m[4] = (short)mm; l[4] = (short)ll;
  split3(b.y, hh, mm, ll); h[5] = (short)hh; m[5] = (short)mm; l[5] = (short)ll;
  split3(b.z, hh, mm, ll); h[6] = (short)hh; m[6] = (short)mm; l[6] = (short)ll;
  split3(b.w, hh, mm, ll); h[7] = (short)hh; m[7] = (short)mm; l[7] = (short)ll;
}

// Pre-kernel: split W into h/m/l bf16 planes (same math as split3).
__global__ __launch_bounds__(256) void split_w_kernel(
    const float* __restrict__ w, unsigned short* __restrict__ wh,
    unsigned short* __restrict__ wm, unsigned short* __restrict__ wl) {
  const int i = (blockIdx.x * 256 + threadIdx.x) * 4;
  float4 v = ld4(w + i);
  ushort4 h4, m4, l4;
  split3(v.x, h4.x, m4.x, l4.x);
  split3(v.y, h4.y, m4.y, l4.y);
  split3(v.z, h4.z, m4.z, l4.z);
  split3(v.w, h4.w, m4.w, l4.w);
  *reinterpret_cast<ushort4*>(wh + i) = h4;
  *reinterpret_cast<ushort4*>(wm + i) = m4;
  *reinterpret_cast<ushort4*>(wl + i) = l4;
}

__global__ __launch_bounds__(BLOCK, 1) void topk_router_mfma(
    const float* __restrict__ x, const unsigned short* __restrict__ wh,
    const unsigned short* __restrict__ wm,
    const unsigned short* __restrict__ wl, const float* __restrict__ bias,
    float* __restrict__ out_final, float* __restrict__ out_idx) {
  __shared__ unsigned short smem_s[2 * BUFS];  // 98304 B; fp32 partials alias

  const int tid = threadIdx.x;
  const int lane = tid & 63;
  const int wid = tid >> 6;
  const int kq = wid & 3;   // K slice (1024 k)
  const int rh = wid >> 2;  // row half (32 rows)
  const int rowBase = blockIdx.x * ROWS_B;
  const int lr = lane & 15;
  const int kg = lane >> 4;

  // Staging: 48 regions (kq,pl,eg) of 1 KB; wave w stages r = 6w+i, i=0..5.
  // Region r: kq=r/12, pl=(r%12)>>2, eg=r&3. Lane ll holds
  // W_pl[eg*16 + (ll&15)][kq*1024 + t*32 + (ll>>4)*8 ..+8) at slot ll*16B.
#define DECL_RG(i)                                                       \
  const int r##i = wid * 6 + (i);                                        \
  const int q##i = r##i >> 2;                                            \
  const int rkq##i = q##i / 3;                                           \
  const int rpl##i = q##i - rkq##i * 3;                                  \
  const unsigned short* gb##i =                                          \
      (rpl##i == 0 ? wh : (rpl##i == 1 ? wm : wl)) +                     \
      (size_t)((r##i & 3) * 16 + lr) * H_DIM + rkq##i * KSLICE + kg * 8; \
  unsigned short* lb##i = &smem_s[r##i * REG_SH];
  DECL_RG(0) DECL_RG(1) DECL_RG(2) DECL_RG(3) DECL_RG(4) DECL_RG(5)

#define STAGE(t, buf)                                  \
  do {                                                 \
    gload16(gb0 + (size_t)(t) * 32, lb0 + (buf)*BUFS); \
    gload16(gb1 + (size_t)(t) * 32, lb1 + (buf)*BUFS); \
    gload16(gb2 + (size_t)(t) * 32, lb2 + (buf)*BUFS); \
    gload16(gb3 + (size_t)(t) * 32, lb3 + (buf)*BUFS); \
    gload16(gb4 + (size_t)(t) * 32, lb4 + (buf)*BUFS); \
    gload16(gb5 + (size_t)(t) * 32, lb5 + (buf)*BUFS); \
  } while (0)

  // X: this wave's 32 rows (2 A-frags) x its 1024-k slice.
  const float* __restrict__ xr0 =
      x + (size_t)(rowBase + rh * 32 + lr) * H_DIM + kq * KSLICE + kg * 8;
  const float* __restrict__ xr1 = xr0 + (size_t)16 * H_DIM;

  float4 xA0, xA1, xA2, xA3, xB0, xB1, xB2, xB3;
#define XLOADA(t)                          \
  do {                                     \
    xA0 = ld4(xr0 + (size_t)(t) * 32);     \
    xA1 = ld4(xr0 + (size_t)(t) * 32 + 4); \
    xA2 = ld4(xr1 + (size_t)(t) * 32);     \
    xA3 = ld4(xr1 + (size_t)(t) * 32 + 4); \
  } while (0)
#define XLOADB(t)                          \
  do {                                     \
    xB0 = ld4(xr0 + (size_t)(t) * 32);     \
    xB1 = ld4(xr0 + (size_t)(t) * 32 + 4); \
    xB2 = ld4(xr1 + (size_t)(t) * 32);     \
    xB3 = ld4(xr1 + (size_t)(t) * 32 + 4); \
  } while (0)

  f32x4 accA0 = {0.f, 0.f, 0.f, 0.f}, accA1 = accA0, accA2 = accA0,
        accA3 = accA0, accB0 = accA0, accB1 = accA0, accB2 = accA0,
        accB3 = accA0;

  // Prologue: stage tile0 -> buf0; X phases 0,1 -> regs; full drain once.
  STAGE(0, 0);
  __builtin_amdgcn_sched_barrier(0);
  XLOADA(0);
  XLOADB(1);
  asm volatile("s_waitcnt vmcnt(0)" ::: "memory");
  __builtin_amdgcn_s_barrier();
  __builtin_amdgcn_sched_barrier(0);

  // Consumer: contiguous 1KB per (eg,pl) region, slot = lane*16B.
#define FRAG(buf, eg, pl)                                                  \
  (*reinterpret_cast<const short8*>(                                       \
      &smem_s[(size_t)(buf)*BUFS + ((kq * 3 + (pl)) * 4 + (eg)) * REG_SH + \
              lane * 8]))

#define MM(d, a, b) d = __builtin_amdgcn_mfma_f32_16x16x32_bf16(a, b, d, 0, 0, 0)
// One product term across all 8 accumulators: 8 independent MFMAs between
// dependent reuses of any acc. Per-acc term order stays hh,hm,mh,mm,hl,lh.
#define TERM8(A0, A1, B0, B1, B2, B3)                   \
  MM(accA0, A0, B0); MM(accB0, A1, B0);                 \
  MM(accA1, A0, B1); MM(accB1, A1, B1);                 \
  MM(accA2, A0, B2); MM(accB2, A1, B2);                 \
  MM(accA3, A0, B3); MM(accB3, A1, B3);

#define PHASE(p, buf, X0, X1, X2, X3, XLOADM)                           \
  do {                                                                  \
    if ((p) + 1 < NPH) STAGE((p) + 1, (buf) ^ 1); /* async, counted */  \
    __builtin_amdgcn_sched_barrier(0); /* stage = oldest vmem ops */    \
    short8 b0h = FRAG(buf, 0, 0), b0m = FRAG(buf, 0, 1),                \
           b0l = FRAG(buf, 0, 2);                                       \
    short8 b1h = FRAG(buf, 1, 0), b1m = FRAG(buf, 1, 1),                \
           b1l = FRAG(buf, 1, 2);                                       \
    short8 b2h = FRAG(buf, 2, 0), b2m = FRAG(buf, 2, 1),                \
           b2l = FRAG(buf, 2, 2);                                       \
    short8 b3h = FRAG(buf, 3, 0), b3m = FRAG(buf, 3, 1),                \
           b3l = FRAG(buf, 3, 2);                                       \
    short8 ah0, am0, al0, ah1, am1, al1;                                \
    split3_8(X0, X1, ah0, am0, al0); /* consume X(p) FIRST */           \
    split3_8(X2, X3, ah1, am1, al1);                                    \
    if ((p) + 2 < NPH) XLOADM((p) + 2); /* THEN prefetch into X regs */ \
    TERM8(ah0, ah1, b0h, b1h, b2h, b3h) /* hh */                        \
    TERM8(ah0, ah1, b0m, b1m, b2m, b3m) /* hm */                        \
    TERM8(am0, am1, b0h, b1h, b2h, b3h) /* mh */                        \
    TERM8(am0, am1, b0m, b1m, b2m, b3m) /* mm */                        \
    TERM8(ah0, ah1, b0l, b1l, b2l, b3l) /* hl */                        \
    TERM8(al0, al1, b0h, b1h, b2h, b3h) /* lh */                        \
    if ((p) + 2 < NPH) {                                                \
      asm volatile("s_waitcnt vmcnt(4)" ::: "memory"); /* stage only */ \
    } else {                                                            \
      asm volatile("s_waitcnt vmcnt(0)" ::: "memory"); /* tail drain */ \
    }                                                                   \
    __builtin_amdgcn_s_barrier();                                       \
    __builtin_amdgcn_sched_barrier(0);                                  \
  } while (0)

  for (int p = 0; p < NPH; p += 2) {
    PHASE(p, 0, xA0, xA1, xA2, xA3, XLOADA);
    PHASE(p + 1, 1, xB0, xB1, xB2, xB3, XLOADB);
  }

  // Partials: part[kq][row][e], row pad 68 floats (69632 B, aliased; loop
  // ended with vmcnt(0)+barrier so all stage ops and reads are done).
  float* part = reinterpret_cast<float*>(smem_s);
  const int pr = kg * 4;
  const int rwA = rh * 32 + pr;       // frag0 rows
  const int rwB = rh * 32 + 16 + pr;  // frag1 rows
#define PSTORE(A, rw, g)                                        \
  part[(size_t)(kq * 64 + (rw) + 0) * 68 + (g)*16 + lr] = A[0]; \
  part[(size_t)(kq * 64 + (rw) + 1) * 68 + (g)*16 + lr] = A[1]; \
  part[(size_t)(kq * 64 + (rw) + 2) * 68 + (g)*16 + lr] = A[2]; \
  part[(size_t)(kq * 64 + (rw) + 3) * 68 + (g)*16 + lr] = A[3];
  PSTORE(accA0, rwA, 0)
  PSTORE(accA1, rwA, 1)
  PSTORE(accA2, rwA, 2)
  PSTORE(accA3, rwA, 3)
  PSTORE(accB0, rwB, 0)
  PSTORE(accB1, rwB, 1)
  PSTORE(accB2, rwB, 2)
  PSTORE(accB3, rwB, 3)
  asm volatile("s_waitcnt lgkmcnt(0)" ::: "memory");
  __builtin_amdgcn_s_barrier();

  // Epilogue: 8 threads/row, 8 experts each; ordered 4-way partial sum,
  // stable top-2 scan, shfl_xor merge, softmax, scatter.
  const int r = tid >> 3;
  const int eb = (tid & 7) * 8;
  const int n = rowBase + r;

  float v8[8];
#pragma unroll
  for (int j = 0; j < 8; ++j) {
    int e = eb + j;
    v8[j] = ((part[(size_t)(0 * 64 + r) * 68 + e] +
              part[(size_t)(1 * 64 + r) * 68 + e]) +
             (part[(size_t)(2 * 64 + r) * 68 + e] +
              part[(size_t)(3 * 64 + r) * 68 + e])) +
            bias[e];
  }

  float av = -INFINITY, bv = -INFINITY;
  int ai = E_EXPERTS, bi = E_EXPERTS;
#pragma unroll
  for (int j = 0; j < 8; ++j) {
    int e = eb + j;
    float v = v8[j];
    bool beats_a = (v > av) || (v == av && e < ai);
    bool beats_b = (v > bv) || (v == bv && e < bi);
    if (beats_a) {
      bv = av; bi = ai; av = v; ai = e;
    } else if (beats_b) {
      bv = v; bi = e;
    }
  }
#pragma unroll
  for (int d = 1; d < 8; d <<= 1) {
    float av2 = __shfl_xor(av, d);
    float bv2 = __shfl_xor(bv, d);
    int ai2 = __shfl_xor(ai, d);
    int bi2 = __shfl_xor(bi, d);
    bool afirst = (av > av2) || (av == av2 && ai < ai2);
    float na, nb;
    int nai, nbi;
    if (afirst) {
      na = av; nai = ai;
      bool t = (bv > av2) || (bv == av2 && bi < ai2);
      nb = t ? bv : av2;
      nbi = t ? bi : ai2;
    } else {
      na = av2; nai = ai2;
      bool t = (av > bv2) || (av == bv2 && ai < bi2);
      nb = t ? av : bv2;
      nbi = t ? ai : bi2;
    }
    av = na; ai = nai; bv = nb; bi = nbi;
  }

  float e1 = expf(bv - av);
  float denom = 1.0f + e1;
  float p0 = 1.0f / denom;
  float p1 = e1 / denom;

#pragma unroll
  for (int i = 0; i < 2; ++i) {
    float4 o4;
    float* po = &o4.x;
#pragma unroll
    for (int j = 0; j < 4; ++j) {
      int e = eb + i * 4 + j;
      po[j] = (e == ai) ? p0 : (e == bi) ? p1 : 0.0f;
    }
    *reinterpret_cast<float4*>(&out_final[(size_t)n * E_EXPERTS + eb + i * 4]) =
        o4;
  }
  if ((tid & 7) == 0) {
    out_idx[(size_t)n * 2 + 0] = (float)ai;
    out_idx[(size_t)n * 2 + 1] = (float)bi;
  }
}

extern "C" void kernel_launch(void* const* d_in, const int* in_sizes, int n_in,
                              void* d_out, int out_size, void* d_ws,
                              size_t ws_size, hipStream_t stream) {
  const float* x = (const float*)d_in[0];
  const float* w = (const float*)d_in[1];
  const float* bias = (const float*)d_in[2];
  const int N = in_sizes[0] / H_DIM;  // 16384
  float* out_final = (float*)d_out;
  float* out_idx = out_final + (size_t)N * E_EXPERTS;

  unsigned short* wh = (unsigned short*)d_ws;  // 3 planes x 512 KB
  unsigned short* wm = wh + W_ELEMS;
  unsigned short* wl = wm + W_ELEMS;

  split_w_kernel<<<W_ELEMS / (256 * 4), 256, 0, stream>>>(w, wh, wm, wl);
  topk_router_mfma<<<N / ROWS_B, BLOCK, 0, stream>>>(x, wh, wm, wl, bias,
                                                     out_final, out_idx);
}